// Round 1
// baseline (26.120 us; speedup 1.0000x reference)
//
#include <hip/hip_runtime.h>
#include <hip/hip_bf16.h>

// Problem constants (from reference)
#define T_LEN 2048
#define D_DIM 64
#define K_CH  8
#define B_SZ  8

// Chunked-scan config
#define CT 64                 // timesteps per chunk
#define NC (T_LEN / CT)       // 32 chunks

__device__ __forceinline__ float2 cmul(float2 a, float2 b) {
    return make_float2(a.x * b.x - a.y * b.y, a.x * b.y + a.y * b.x);
}

// Kernel 1: per (b, chunk, k, d) compute chunk-local scan final state with
// zero initial state:  S = sum_{j=0}^{CT-1} A^{CT-1-j} * h[c_start + j]
__global__ __launch_bounds__(512) void s4d_carry(
    const float* __restrict__ h,
    const float* __restrict__ log_neg_re,
    const float* __restrict__ imag,
    const float* __restrict__ log_dt,
    float2* __restrict__ carries)
{
    const int bc = blockIdx.x;
    const int b = bc / NC;
    const int c = bc % NC;
    const int tid = threadIdx.x;       // 0..511
    const int k = tid >> 6;            // wave-uniform (64 lanes per k)
    const int d = tid & 63;

    const float dt = expf(log_dt[0]);
    const float re = -expf(log_neg_re[k]);
    const float im = imag[k];
    const float mag = expf(re * dt);
    const float2 A = make_float2(mag * cosf(im * dt), mag * sinf(im * dt));

    const float* hp = h + ((size_t)b * T_LEN + (size_t)c * CT) * D_DIM + d;

    float2 x = make_float2(0.f, 0.f);
    #pragma unroll 8
    for (int t = 0; t < CT; ++t) {
        float hv = hp[(size_t)t * D_DIM];   // 64 lanes -> 256B coalesced
        x = cmul(A, x);
        x.x += hv;
    }
    carries[((size_t)(b * NC + c) * K_CH + k) * D_DIM + d] = x;
}

// Kernel 2: per (b, chunk) block. Each thread combines carries of preceding
// chunks (<= NC-1 sequential complex mul-adds) to get its init state, then
// replays the chunk emitting out[b,t,k,d] = 2*Re(Bbar_k * x[t]).
__global__ __launch_bounds__(512) void s4d_out(
    const float* __restrict__ h,
    const float* __restrict__ log_neg_re,
    const float* __restrict__ imag,
    const float* __restrict__ B_proj,
    const float* __restrict__ log_dt,
    const float2* __restrict__ carries,
    float* __restrict__ out)
{
    const int bc = blockIdx.x;
    const int b = bc / NC;
    const int c = bc % NC;
    const int tid = threadIdx.x;
    const int k = tid >> 6;
    const int d = tid & 63;

    const float dt = expf(log_dt[0]);
    const float re = -expf(log_neg_re[k]);
    const float im = imag[k];
    const float mag = expf(re * dt);
    const float2 A = make_float2(mag * cosf(im * dt), mag * sinf(im * dt));

    // A^CT in closed form (matches reference's closed-form powers)
    const float magC = expf(re * dt * (float)CT);
    const float angC = im * dt * (float)CT;
    const float2 Act = make_float2(magC * cosf(angC), magC * sinf(angC));

    // Bbar = (A - 1)/eig * B_proj ; fold factor 2 in: C2 = 2*Bbar
    const float inv = 1.f / (re * re + im * im);
    const float2 num = make_float2(A.x - 1.f, A.y);
    const float bp = B_proj[k];
    const float2 C2v = make_float2(2.f * bp * (num.x * re + num.y * im) * inv,
                                   2.f * bp * (num.y * re - num.x * im) * inv);

    // Prefix-combine carries of chunks 0..c-1 (all in L2: 1 MB total)
    const float2* cp = carries + ((size_t)b * NC * K_CH + (size_t)k) * D_DIM + d;
    float2 x = make_float2(0.f, 0.f);
    for (int c2 = 0; c2 < c; ++c2) {
        float2 s = cp[(size_t)c2 * (K_CH * D_DIM)];
        x = cmul(Act, x);
        x.x += s.x;
        x.y += s.y;
    }

    const float* hp = h + ((size_t)b * T_LEN + (size_t)c * CT) * D_DIM + d;
    float* op = out + (((size_t)b * T_LEN + (size_t)c * CT) * K_CH + k) * D_DIM + d;

    #pragma unroll 8
    for (int t = 0; t < CT; ++t) {
        float hv = hp[(size_t)t * D_DIM];
        x = cmul(A, x);
        x.x += hv;
        op[(size_t)t * (K_CH * D_DIM)] = C2v.x * x.x - C2v.y * x.y;  // 256B coalesced store per wave
    }
}

extern "C" void kernel_launch(void* const* d_in, const int* in_sizes, int n_in,
                              void* d_out, int out_size, void* d_ws, size_t ws_size,
                              hipStream_t stream) {
    const float* h          = (const float*)d_in[0];
    const float* log_neg_re = (const float*)d_in[1];
    const float* imag       = (const float*)d_in[2];
    const float* B_proj     = (const float*)d_in[3];
    const float* log_dt     = (const float*)d_in[4];
    float* out = (float*)d_out;

    // carries: B * NC * K * D complex floats = 1 MiB (fits d_ws)
    float2* carries = (float2*)d_ws;

    dim3 grid(B_SZ * NC);
    dim3 block(512);
    hipLaunchKernelGGL(s4d_carry, grid, block, 0, stream,
                       h, log_neg_re, imag, log_dt, carries);
    hipLaunchKernelGGL(s4d_out, grid, block, 0, stream,
                       h, log_neg_re, imag, B_proj, log_dt, carries, out);
}

// Round 3
// 25.466 us; speedup vs baseline: 1.0257x; 1.0257x over previous
//
#include <hip/hip_runtime.h>
#include <hip/hip_bf16.h>

// Problem constants (from reference)
#define T_LEN 2048
#define D_DIM 64
#define K_CH  8
#define B_SZ  8

// Chunked-scan config: 512 blocks = 2 blocks/CU, 16 waves/CU
#define CT 32                 // timesteps per chunk
#define NC (T_LEN / CT)       // 64 chunks

__device__ __forceinline__ float2 cmul(float2 a, float2 b) {
    return make_float2(a.x * b.x - a.y * b.y, a.x * b.y + a.y * b.x);
}
__device__ __forceinline__ float2 cadd(float2 a, float2 b) {
    return make_float2(a.x + b.x, a.y + b.y);
}

// Kernel 1: per (b, chunk, k, d) compute chunk-local scan final state with
// zero initial state:  S = sum_{j=0}^{CT-1} A^{CT-1-j} * h[c_start + j]
__global__ __launch_bounds__(512) void s4d_carry(
    const float* __restrict__ h,
    const float* __restrict__ log_neg_re,
    const float* __restrict__ imag,
    const float* __restrict__ log_dt,
    float2* __restrict__ carries)
{
    const int bc = blockIdx.x;
    const int b = bc / NC;
    const int c = bc % NC;
    const int tid = threadIdx.x;       // 0..511
    const int k = tid >> 6;            // wave-uniform (64 lanes per k)
    const int d = tid & 63;

    const float dt = expf(log_dt[0]);
    const float re = -expf(log_neg_re[k]);
    const float im = imag[k];
    const float mag = expf(re * dt);
    const float2 A = make_float2(mag * cosf(im * dt), mag * sinf(im * dt));

    const float* hp = h + ((size_t)b * T_LEN + (size_t)c * CT) * D_DIM + d;

    float2 x = make_float2(0.f, 0.f);
    #pragma unroll 8
    for (int t = 0; t < CT; ++t) {
        float hv = hp[(size_t)t * D_DIM];   // 64 lanes -> 256B coalesced
        x = cmul(A, x);
        x.x += hv;
    }
    carries[((size_t)(b * NC + c) * K_CH + k) * D_DIM + d] = x;
}

// Kernel 2: per (b, chunk) block. Each thread combines carries of preceding
// chunks (grouped by 4 to shorten the dependent chain) to get its init
// state, then replays the chunk emitting out[b,t,k,d] = 2*Re(Bbar_k * x[t]).
__global__ __launch_bounds__(512) void s4d_out(
    const float* __restrict__ h,
    const float* __restrict__ log_neg_re,
    const float* __restrict__ imag,
    const float* __restrict__ B_proj,
    const float* __restrict__ log_dt,
    const float2* __restrict__ carries,
    float* __restrict__ out)
{
    const int bc = blockIdx.x;
    const int b = bc / NC;
    const int c = bc % NC;
    const int tid = threadIdx.x;
    const int k = tid >> 6;
    const int d = tid & 63;

    const float dt = expf(log_dt[0]);
    const float re = -expf(log_neg_re[k]);
    const float im = imag[k];
    const float mag = expf(re * dt);
    const float2 A = make_float2(mag * cosf(im * dt), mag * sinf(im * dt));

    // A^CT in closed form (matches reference's closed-form powers)
    const float magC = expf(re * dt * (float)CT);
    const float angC = im * dt * (float)CT;
    const float2 Act  = make_float2(magC * cosf(angC), magC * sinf(angC));
    const float2 Act2 = cmul(Act, Act);
    const float2 Act3 = cmul(Act2, Act);
    const float2 Act4 = cmul(Act2, Act2);

    // Bbar = (A - 1)/eig * B_proj ; fold factor 2 in: C2 = 2*Bbar
    const float inv = 1.f / (re * re + im * im);
    const float2 num = make_float2(A.x - 1.f, A.y);
    const float bp = B_proj[k];
    const float2 C2v = make_float2(2.f * bp * (num.x * re + num.y * im) * inv,
                                   2.f * bp * (num.y * re - num.x * im) * inv);

    // Prefix-combine carries of chunks 0..c-1 (L2-resident), 4 at a time
    const float2* cp = carries + ((size_t)b * NC * K_CH + (size_t)k) * D_DIM + d;
    const size_t cstride = (size_t)K_CH * D_DIM;
    float2 x = make_float2(0.f, 0.f);
    int c2 = 0;
    for (; c2 + 4 <= c; c2 += 4) {
        float2 s0 = cp[(size_t)(c2 + 0) * cstride];
        float2 s1 = cp[(size_t)(c2 + 1) * cstride];
        float2 s2 = cp[(size_t)(c2 + 2) * cstride];
        float2 s3 = cp[(size_t)(c2 + 3) * cstride];
        float2 t01 = cadd(cmul(Act3, s0), cmul(Act2, s1));
        float2 t23 = cadd(cmul(Act, s2), s3);
        x = cadd(cmul(Act4, x), cadd(t01, t23));
    }
    for (; c2 < c; ++c2) {
        float2 s = cp[(size_t)c2 * cstride];
        x = cadd(cmul(Act, x), s);
    }

    const float* hp = h + ((size_t)b * T_LEN + (size_t)c * CT) * D_DIM + d;
    float* op = out + (((size_t)b * T_LEN + (size_t)c * CT) * K_CH + k) * D_DIM + d;

    #pragma unroll 8
    for (int t = 0; t < CT; ++t) {
        float hv = hp[(size_t)t * D_DIM];
        x = cmul(A, x);
        x.x += hv;
        op[(size_t)t * (K_CH * D_DIM)] = C2v.x * x.x - C2v.y * x.y;  // 256B coalesced store per wave
    }
}

extern "C" void kernel_launch(void* const* d_in, const int* in_sizes, int n_in,
                              void* d_out, int out_size, void* d_ws, size_t ws_size,
                              hipStream_t stream) {
    const float* h          = (const float*)d_in[0];
    const float* log_neg_re = (const float*)d_in[1];
    const float* imag       = (const float*)d_in[2];
    const float* B_proj     = (const float*)d_in[3];
    const float* log_dt     = (const float*)d_in[4];
    float* out = (float*)d_out;

    // carries: B * NC * K * D complex floats = 2 MiB (fits d_ws)
    float2* carries = (float2*)d_ws;

    dim3 grid(B_SZ * NC);
    dim3 block(512);
    hipLaunchKernelGGL(s4d_carry, grid, block, 0, stream,
                       h, log_neg_re, imag, log_dt, carries);
    hipLaunchKernelGGL(s4d_out, grid, block, 0, stream,
                       h, log_neg_re, imag, B_proj, log_dt, carries, out);
}